// Round 9
// baseline (267.255 us; speedup 1.0000x reference)
//
#include <hip/hip_runtime.h>

#define N_NODES 75000
#define N_EDGES 1200000
#define DIM 64
#define SCAN_BLK 1024
#define N_SCAN_BLKS ((N_NODES + SCAN_BLK - 1) / SCAN_BLK)   // 74

// Broadcast lane l (wave-uniform) of v to all lanes via v_readlane (VALU).
__device__ __forceinline__ float lane_bcf(float v, int l) {
    return __int_as_float(__builtin_amdgcn_readlane(__float_as_int(v), l));
}
__device__ __forceinline__ int lane_bci(int v, int l) {
    return __builtin_amdgcn_readlane(v, l);
}

// ---------------------------------------------------------------------------
// Kernel A (f64): a[d] = sum_j e1[j]*w_k[j][d];  b[d] = sum_j e2[j]*w_q[j][d]
// ---------------------------------------------------------------------------
__global__ void vec_precompute(const float* __restrict__ w_q,
                               const float* __restrict__ w_k,
                               const float* __restrict__ e1,
                               const float* __restrict__ e2,
                               double* __restrict__ a,
                               double* __restrict__ b) {
    int t = threadIdx.x;
    if (t < DIM) {
        double s = 0.0;
        #pragma unroll
        for (int j = 0; j < DIM; ++j) s += (double)e1[j] * (double)w_k[j * DIM + t];
        a[t] = s;
    } else if (t < 2 * DIM) {
        int d = t - DIM;
        double s = 0.0;
        #pragma unroll
        for (int j = 0; j < DIM; ++j) s += (double)e2[j] * (double)w_q[j * DIM + d];
        b[d] = s;
    }
}

// ---------------------------------------------------------------------------
// Fused node precompute: ONE WAVE PER NODE (grid-strided). Unchanged from R8.
// ---------------------------------------------------------------------------
__global__ __launch_bounds__(256, 4) void node_wave(
    const float* __restrict__ d_u, const float* __restrict__ p_u,
    const float* __restrict__ w_v,
    const double* __restrict__ a_vec, const double* __restrict__ b_vec,
    double* __restrict__ h_src, double* __restrict__ h_dst,
    float* __restrict__ wv_out) {
    int lane = threadIdx.x & 63;
    int wave = (blockIdx.x * 256 + threadIdx.x) >> 6;
    int nwaves = gridDim.x * 4;

    float w[DIM];
    const float4* wr = (const float4*)(w_v + (size_t)lane * DIM);
    #pragma unroll
    for (int k = 0; k < DIM / 4; ++k) {
        float4 v = wr[k];
        w[4 * k + 0] = v.x; w[4 * k + 1] = v.y;
        w[4 * k + 2] = v.z; w[4 * k + 3] = v.w;
    }
    double al = a_vec[lane];
    double bl = b_vec[lane];

    for (int i = wave; i < N_NODES; i += nwaves) {
        float pl = p_u[(size_t)i * DIM + lane];
        float dl = d_u[(size_t)i * DIM + lane];

        double hs = (double)pl * al;
        #pragma unroll
        for (int off = 32; off > 0; off >>= 1) hs += __shfl_xor(hs, off, 64);
        double hd = (double)dl * bl;
        #pragma unroll
        for (int off = 32; off > 0; off >>= 1) hd += __shfl_xor(hd, off, 64);
        if (lane == 0) { h_src[i] = hs; h_dst[i] = hd; }

        float a0 = 0.f, a1 = 0.f, a2 = 0.f, a3 = 0.f;
        #pragma unroll
        for (int d = 0; d < DIM; d += 4) {
            a0 += w[d + 0] * lane_bcf(pl, d + 0);
            a1 += w[d + 1] * lane_bcf(pl, d + 1);
            a2 += w[d + 2] * lane_bcf(pl, d + 2);
            a3 += w[d + 3] * lane_bcf(pl, d + 3);
        }
        wv_out[(size_t)i * DIM + lane] = (a0 + a1) + (a2 + a3);
    }
}

// ---------------------------------------------------------------------------
// CSR step 1: histogram + rank. 4 edges/thread grid-strided -> 4 independent
// atomics in flight per lane (latency hiding).
// ---------------------------------------------------------------------------
#define HIST_BLKS 1172
__global__ __launch_bounds__(256) void hist_kernel(
    const int* __restrict__ dst, int* __restrict__ cnt,
    int* __restrict__ rank) {
    int t = blockIdx.x * 256 + threadIdx.x;
    const int T = HIST_BLKS * 256;
    #pragma unroll
    for (int k = 0; k < 4; ++k) {
        int e = t + k * T;
        if (e < N_EDGES) rank[e] = atomicAdd(&cnt[dst[e]], 1);
    }
}

// CSR step 2a: per-block exclusive scan (Hillis-Steele in LDS).
__global__ __launch_bounds__(SCAN_BLK) void scan1_kernel(
    const int* __restrict__ cnt, int* __restrict__ row,
    int* __restrict__ bsum) {
    __shared__ int sh[SCAN_BLK];
    int tid = threadIdx.x;
    int i = blockIdx.x * SCAN_BLK + tid;
    int v = (i < N_NODES) ? cnt[i] : 0;
    sh[tid] = v;
    __syncthreads();
    for (int off = 1; off < SCAN_BLK; off <<= 1) {
        int t = (tid >= off) ? sh[tid - off] : 0;
        __syncthreads();
        sh[tid] += t;
        __syncthreads();
    }
    if (i < N_NODES) row[i] = sh[tid] - v;   // exclusive
    if (tid == SCAN_BLK - 1) bsum[blockIdx.x] = sh[tid];
}

// CSR step 2b: add block-sum prefix (redundant tiny scan per block).
__global__ __launch_bounds__(256) void scan23_kernel(
    int* __restrict__ row, const int* __restrict__ bsum) {
    __shared__ int pref[N_SCAN_BLKS];
    int tid = threadIdx.x;
    if (tid == 0) {
        int run = 0;
        #pragma unroll 8
        for (int k = 0; k < N_SCAN_BLKS; ++k) { pref[k] = run; run += bsum[k]; }
    }
    __syncthreads();
    int i = blockIdx.x * 256 + tid;
    if (i >= N_NODES) return;
    row[i] += pref[i / SCAN_BLK];
}

// CSR step 3: atomic-free scatter of src ids. 2 edges/thread for store ILP.
#define BUILD_BLKS 2344
__global__ __launch_bounds__(256) void build_kernel(
    const int* __restrict__ src, const int* __restrict__ dst,
    const int* __restrict__ row, const int* __restrict__ rank,
    int* __restrict__ csr_src) {
    int t = blockIdx.x * 256 + threadIdx.x;
    const int T = BUILD_BLKS * 256;
    #pragma unroll
    for (int k = 0; k < 2; ++k) {
        int e = t + k * T;
        if (e < N_EDGES) {
            int pos = row[dst[e]] + rank[e];
            csr_src[pos] = src[e];
        }
    }
}

// ---------------------------------------------------------------------------
// Gather: one wave per dst node, lane = dim.
//   denom: f64 butterfly (bit-identical to R8 — precision path).
//   Inner loop: edge j broadcast via READLANE (uniform j -> VALU, no LDS
//   pipe, no lgkmcnt). Per edge: one coalesced 256B dword row load + FMA.
//   Unrolled x4 -> 4 independent gather loads in flight.
// ---------------------------------------------------------------------------
__global__ __launch_bounds__(256) void node_gather(
    const int* __restrict__ row, const int* __restrict__ cnt,
    const int* __restrict__ csr_src,
    const double* __restrict__ h_src, const double* __restrict__ h_dst,
    const float* __restrict__ wv, float* __restrict__ out) {
    int gtid = blockIdx.x * 256 + threadIdx.x;
    int node = gtid >> 6;
    int lane = threadIdx.x & 63;
    if (node >= N_NODES) return;

    int start = row[node];
    int deg = cnt[node];
    double hd = h_dst[node];

    if (deg <= 64) {
        int s0 = 0;
        double c0 = 0.0;
        if (lane < deg) {
            s0 = csr_src[start + lane];
            c0 = h_src[s0] + hd;
        }
        // denom: f64 butterfly (identical order to previous rounds)
        double r = c0;
        #pragma unroll
        for (int off = 32; off > 0; off >>= 1) r += __shfl_xor(r, off, 64);
        double inv = 1.0 / r;
        float cf0 = (lane < deg) ? (float)(c0 * inv) : 0.f;

        float acc = 0.f;
        int j = 0;
        for (; j + 4 <= deg; j += 4) {
            int sA = lane_bci(s0, j + 0); float cA = lane_bcf(cf0, j + 0);
            int sB = lane_bci(s0, j + 1); float cB = lane_bcf(cf0, j + 1);
            int sC = lane_bci(s0, j + 2); float cC = lane_bcf(cf0, j + 2);
            int sD = lane_bci(s0, j + 3); float cD = lane_bcf(cf0, j + 3);
            float wA = wv[(size_t)sA * DIM + lane];
            float wB = wv[(size_t)sB * DIM + lane];
            float wC = wv[(size_t)sC * DIM + lane];
            float wD = wv[(size_t)sD * DIM + lane];
            acc += wA * cA;
            acc += wB * cB;
            acc += wC * cC;
            acc += wD * cD;
        }
        for (; j < deg; ++j) {
            int s = lane_bci(s0, j); float cf = lane_bcf(cf0, j);
            acc += wv[(size_t)s * DIM + lane] * cf;
        }
        out[(size_t)node * DIM + lane] = acc;
    } else {
        // --- rare fallback (deg > 64): chunked, readlane broadcasts ---
        double denom = 0.0;
        for (int base = 0; base < deg; base += 64) {
            int m = deg - base; if (m > 64) m = 64;
            double c = 0.0;
            if (lane < m) {
                int s = csr_src[start + base + lane];
                c = h_src[s] + hd;
            }
            #pragma unroll
            for (int off = 32; off > 0; off >>= 1) c += __shfl_xor(c, off, 64);
            denom += c;
        }
        double inv = 1.0 / denom;
        float acc = 0.f;
        for (int base = 0; base < deg; base += 64) {
            int m = deg - base; if (m > 64) m = 64;
            int s1 = 0; float cf1 = 0.f;
            if (lane < m) {
                s1 = csr_src[start + base + lane];
                cf1 = (float)((h_src[s1] + hd) * inv);
            }
            for (int j = 0; j < m; ++j) {
                int s = lane_bci(s1, j);
                float cf = lane_bcf(cf1, j);
                acc += wv[(size_t)s * DIM + lane] * cf;
            }
        }
        out[(size_t)node * DIM + lane] = acc;
    }
}

// ---------------------------------------------------------------------------
// Launch
// ---------------------------------------------------------------------------
extern "C" void kernel_launch(void* const* d_in, const int* in_sizes, int n_in,
                              void* d_out, int out_size, void* d_ws, size_t ws_size,
                              hipStream_t stream) {
    const float* d_u = (const float*)d_in[0];
    const float* p_u = (const float*)d_in[1];
    const float* w_q = (const float*)d_in[2];
    const float* w_k = (const float*)d_in[3];
    const float* w_v = (const float*)d_in[4];
    const float* e1  = (const float*)d_in[5];
    const float* e2  = (const float*)d_in[6];
    const int*   src = (const int*)d_in[7];
    const int*   dst = (const int*)d_in[8];
    float* out = (float*)d_out;

    // Workspace: doubles first (8B aligned), then floats, then ints.
    double* a      = (double*)d_ws;
    double* b      = a + DIM;
    double* h_src  = b + DIM;
    double* h_dst  = h_src + N_NODES;
    float*  wv     = (float*)(h_dst + N_NODES);       // N_NODES*DIM floats
    int*    cnt    = (int*)(wv + (size_t)N_NODES * DIM);
    int*    row    = cnt + N_NODES;
    int*    bsum   = row + N_NODES;                   // 128 ints
    int*    rank   = bsum + 128;                      // N_EDGES ints
    int*    csr_src= rank + N_EDGES;                  // N_EDGES ints

    vec_precompute<<<1, 128, 0, stream>>>(w_q, w_k, e1, e2, a, b);

    hipMemsetAsync(cnt, 0, sizeof(int) * N_NODES, stream);

    hist_kernel<<<HIST_BLKS, 256, 0, stream>>>(dst, cnt, rank);

    node_wave<<<1024, 256, 0, stream>>>(
        d_u, p_u, w_v, a, b, h_src, h_dst, wv);

    scan1_kernel<<<N_SCAN_BLKS, SCAN_BLK, 0, stream>>>(cnt, row, bsum);
    scan23_kernel<<<(N_NODES + 255) / 256, 256, 0, stream>>>(row, bsum);

    build_kernel<<<BUILD_BLKS, 256, 0, stream>>>(
        src, dst, row, rank, csr_src);

    node_gather<<<(N_NODES * 64 + 255) / 256, 256, 0, stream>>>(
        row, cnt, csr_src, h_src, h_dst, wv, out);
}

// Round 10
// 258.730 us; speedup vs baseline: 1.0329x; 1.0329x over previous
//
#include <hip/hip_runtime.h>

#define N_NODES 75000
#define N_EDGES 1200000
#define DIM 64
#define SCAN_BLK 1024
#define N_SCAN_BLKS ((N_NODES + SCAN_BLK - 1) / SCAN_BLK)   // 74
#define NCOPY 8
#define HIST_BLKS ((N_EDGES + 1023) / 1024)                 // 1172, 1024 edges/block

// Broadcast lane l (wave-uniform) of v to all lanes via v_readlane (VALU).
__device__ __forceinline__ float lane_bcf(float v, int l) {
    return __int_as_float(__builtin_amdgcn_readlane(__float_as_int(v), l));
}
__device__ __forceinline__ int lane_bci(int v, int l) {
    return __builtin_amdgcn_readlane(v, l);
}

// ---------------------------------------------------------------------------
// Kernel A (f64): a[d] = sum_j e1[j]*w_k[j][d];  b[d] = sum_j e2[j]*w_q[j][d]
// ---------------------------------------------------------------------------
__global__ void vec_precompute(const float* __restrict__ w_q,
                               const float* __restrict__ w_k,
                               const float* __restrict__ e1,
                               const float* __restrict__ e2,
                               double* __restrict__ a,
                               double* __restrict__ b) {
    int t = threadIdx.x;
    if (t < DIM) {
        double s = 0.0;
        #pragma unroll
        for (int j = 0; j < DIM; ++j) s += (double)e1[j] * (double)w_k[j * DIM + t];
        a[t] = s;
    } else if (t < 2 * DIM) {
        int d = t - DIM;
        double s = 0.0;
        #pragma unroll
        for (int j = 0; j < DIM; ++j) s += (double)e2[j] * (double)w_q[j * DIM + d];
        b[d] = s;
    }
}

// ---------------------------------------------------------------------------
// Fused node precompute: ONE WAVE PER NODE (grid-strided). Unchanged from R8.
// ---------------------------------------------------------------------------
__global__ __launch_bounds__(256, 4) void node_wave(
    const float* __restrict__ d_u, const float* __restrict__ p_u,
    const float* __restrict__ w_v,
    const double* __restrict__ a_vec, const double* __restrict__ b_vec,
    double* __restrict__ h_src, double* __restrict__ h_dst,
    float* __restrict__ wv_out) {
    int lane = threadIdx.x & 63;
    int wave = (blockIdx.x * 256 + threadIdx.x) >> 6;
    int nwaves = gridDim.x * 4;

    float w[DIM];
    const float4* wr = (const float4*)(w_v + (size_t)lane * DIM);
    #pragma unroll
    for (int k = 0; k < DIM / 4; ++k) {
        float4 v = wr[k];
        w[4 * k + 0] = v.x; w[4 * k + 1] = v.y;
        w[4 * k + 2] = v.z; w[4 * k + 3] = v.w;
    }
    double al = a_vec[lane];
    double bl = b_vec[lane];

    for (int i = wave; i < N_NODES; i += nwaves) {
        float pl = p_u[(size_t)i * DIM + lane];
        float dl = d_u[(size_t)i * DIM + lane];

        double hs = (double)pl * al;
        #pragma unroll
        for (int off = 32; off > 0; off >>= 1) hs += __shfl_xor(hs, off, 64);
        double hd = (double)dl * bl;
        #pragma unroll
        for (int off = 32; off > 0; off >>= 1) hd += __shfl_xor(hd, off, 64);
        if (lane == 0) { h_src[i] = hs; h_dst[i] = hd; }

        float a0 = 0.f, a1 = 0.f, a2 = 0.f, a3 = 0.f;
        #pragma unroll
        for (int d = 0; d < DIM; d += 4) {
            a0 += w[d + 0] * lane_bcf(pl, d + 0);
            a1 += w[d + 1] * lane_bcf(pl, d + 1);
            a2 += w[d + 2] * lane_bcf(pl, d + 2);
            a3 += w[d + 3] * lane_bcf(pl, d + 3);
        }
        wv_out[(size_t)i * DIM + lane] = (a0 + a1) + (a2 + a3);
    }
}

// ---------------------------------------------------------------------------
// CSR step 1: XCD-privatized histogram. Block B (1024 contiguous edges)
// atomics into copy B&7 — with round-robin block->XCD dispatch each copy
// stays XCD-local in that XCD's L2, eliminating cross-XCD line ping-pong.
// rank[e] = rank within (copy, dst). copy is recomputable: copy(e)=(e>>10)&7.
// ---------------------------------------------------------------------------
__global__ __launch_bounds__(256) void hist_kernel(
    const int* __restrict__ dst, int* __restrict__ cnt8,
    int* __restrict__ rank) {
    int base = blockIdx.x << 10;                 // 1024 edges per block
    int* mycnt = cnt8 + (size_t)(blockIdx.x & (NCOPY - 1)) * N_NODES;
    #pragma unroll
    for (int k = 0; k < 4; ++k) {
        int e = base + k * 256 + threadIdx.x;
        if (e < N_EDGES) rank[e] = atomicAdd(&mycnt[dst[e]], 1);
    }
}

// CSR step 2a: fold the 8 copies (in-place exclusive prefix over copies ->
// per-copy base offsets for build), total degree -> cnt; then per-block
// exclusive scan of totals (Hillis-Steele in LDS).
__global__ __launch_bounds__(SCAN_BLK) void scan1_kernel(
    int* __restrict__ cnt8, int* __restrict__ cnt,
    int* __restrict__ row, int* __restrict__ bsum) {
    __shared__ int sh[SCAN_BLK];
    int tid = threadIdx.x;
    int i = blockIdx.x * SCAN_BLK + tid;
    int v = 0;
    if (i < N_NODES) {
        int run = 0;
        #pragma unroll
        for (int c = 0; c < NCOPY; ++c) {
            int x = cnt8[(size_t)c * N_NODES + i];
            cnt8[(size_t)c * N_NODES + i] = run;   // P[c][i] = prefix
            run += x;
        }
        v = run;
        cnt[i] = run;                              // degree
    }
    sh[tid] = v;
    __syncthreads();
    for (int off = 1; off < SCAN_BLK; off <<= 1) {
        int t = (tid >= off) ? sh[tid - off] : 0;
        __syncthreads();
        sh[tid] += t;
        __syncthreads();
    }
    if (i < N_NODES) row[i] = sh[tid] - v;   // exclusive
    if (tid == SCAN_BLK - 1) bsum[blockIdx.x] = sh[tid];
}

// CSR step 2b: add block-sum prefix (redundant tiny scan per block).
__global__ __launch_bounds__(256) void scan23_kernel(
    int* __restrict__ row, const int* __restrict__ bsum) {
    __shared__ int pref[N_SCAN_BLKS];
    int tid = threadIdx.x;
    if (tid == 0) {
        int run = 0;
        #pragma unroll 8
        for (int k = 0; k < N_SCAN_BLKS; ++k) { pref[k] = run; run += bsum[k]; }
    }
    __syncthreads();
    int i = blockIdx.x * 256 + tid;
    if (i >= N_NODES) return;
    row[i] += pref[i / SCAN_BLK];
}

// CSR step 3: atomic-free scatter of src ids.
//   pos = row[d] + P[copy(e)][d] + rank[e],  copy(e) = (e>>10)&7.
__global__ __launch_bounds__(256) void build_kernel(
    const int* __restrict__ src, const int* __restrict__ dst,
    const int* __restrict__ row, const int* __restrict__ cnt8,
    const int* __restrict__ rank, int* __restrict__ csr_src) {
    int e = blockIdx.x * 256 + threadIdx.x;
    if (e >= N_EDGES) return;
    int d = dst[e];
    int copy = (e >> 10) & (NCOPY - 1);
    int pos = row[d] + cnt8[(size_t)copy * N_NODES + d] + rank[e];
    csr_src[pos] = src[e];
}

// ---------------------------------------------------------------------------
// Gather: one wave per dst node (unchanged from R9: readlane broadcasts,
// x4-unrolled coalesced row gathers; f64 butterfly denom = precision path).
// ---------------------------------------------------------------------------
__global__ __launch_bounds__(256) void node_gather(
    const int* __restrict__ row, const int* __restrict__ cnt,
    const int* __restrict__ csr_src,
    const double* __restrict__ h_src, const double* __restrict__ h_dst,
    const float* __restrict__ wv, float* __restrict__ out) {
    int gtid = blockIdx.x * 256 + threadIdx.x;
    int node = gtid >> 6;
    int lane = threadIdx.x & 63;
    if (node >= N_NODES) return;

    int start = row[node];
    int deg = cnt[node];
    double hd = h_dst[node];

    if (deg <= 64) {
        int s0 = 0;
        double c0 = 0.0;
        if (lane < deg) {
            s0 = csr_src[start + lane];
            c0 = h_src[s0] + hd;
        }
        double r = c0;
        #pragma unroll
        for (int off = 32; off > 0; off >>= 1) r += __shfl_xor(r, off, 64);
        double inv = 1.0 / r;
        float cf0 = (lane < deg) ? (float)(c0 * inv) : 0.f;

        float acc = 0.f;
        int j = 0;
        for (; j + 4 <= deg; j += 4) {
            int sA = lane_bci(s0, j + 0); float cA = lane_bcf(cf0, j + 0);
            int sB = lane_bci(s0, j + 1); float cB = lane_bcf(cf0, j + 1);
            int sC = lane_bci(s0, j + 2); float cC = lane_bcf(cf0, j + 2);
            int sD = lane_bci(s0, j + 3); float cD = lane_bcf(cf0, j + 3);
            float wA = wv[(size_t)sA * DIM + lane];
            float wB = wv[(size_t)sB * DIM + lane];
            float wC = wv[(size_t)sC * DIM + lane];
            float wD = wv[(size_t)sD * DIM + lane];
            acc += wA * cA;
            acc += wB * cB;
            acc += wC * cC;
            acc += wD * cD;
        }
        for (; j < deg; ++j) {
            int s = lane_bci(s0, j); float cf = lane_bcf(cf0, j);
            acc += wv[(size_t)s * DIM + lane] * cf;
        }
        out[(size_t)node * DIM + lane] = acc;
    } else {
        double denom = 0.0;
        for (int base = 0; base < deg; base += 64) {
            int m = deg - base; if (m > 64) m = 64;
            double c = 0.0;
            if (lane < m) {
                int s = csr_src[start + base + lane];
                c = h_src[s] + hd;
            }
            #pragma unroll
            for (int off = 32; off > 0; off >>= 1) c += __shfl_xor(c, off, 64);
            denom += c;
        }
        double inv = 1.0 / denom;
        float acc = 0.f;
        for (int base = 0; base < deg; base += 64) {
            int m = deg - base; if (m > 64) m = 64;
            int s1 = 0; float cf1 = 0.f;
            if (lane < m) {
                s1 = csr_src[start + base + lane];
                cf1 = (float)((h_src[s1] + hd) * inv);
            }
            for (int j = 0; j < m; ++j) {
                int s = lane_bci(s1, j);
                float cf = lane_bcf(cf1, j);
                acc += wv[(size_t)s * DIM + lane] * cf;
            }
        }
        out[(size_t)node * DIM + lane] = acc;
    }
}

// ---------------------------------------------------------------------------
// Launch
// ---------------------------------------------------------------------------
extern "C" void kernel_launch(void* const* d_in, const int* in_sizes, int n_in,
                              void* d_out, int out_size, void* d_ws, size_t ws_size,
                              hipStream_t stream) {
    const float* d_u = (const float*)d_in[0];
    const float* p_u = (const float*)d_in[1];
    const float* w_q = (const float*)d_in[2];
    const float* w_k = (const float*)d_in[3];
    const float* w_v = (const float*)d_in[4];
    const float* e1  = (const float*)d_in[5];
    const float* e2  = (const float*)d_in[6];
    const int*   src = (const int*)d_in[7];
    const int*   dst = (const int*)d_in[8];
    float* out = (float*)d_out;

    // Workspace: doubles first (8B aligned), then floats, then ints.
    double* a      = (double*)d_ws;
    double* b      = a + DIM;
    double* h_src  = b + DIM;
    double* h_dst  = h_src + N_NODES;
    float*  wv     = (float*)(h_dst + N_NODES);       // N_NODES*DIM floats
    int*    cnt    = (int*)(wv + (size_t)N_NODES * DIM);
    int*    row    = cnt + N_NODES;
    int*    bsum   = row + N_NODES;                   // 128 ints
    int*    cnt8   = bsum + 128;                      // NCOPY*N_NODES ints
    int*    rank   = cnt8 + (size_t)NCOPY * N_NODES;  // N_EDGES ints
    int*    csr_src= rank + N_EDGES;                  // N_EDGES ints

    vec_precompute<<<1, 128, 0, stream>>>(w_q, w_k, e1, e2, a, b);

    hipMemsetAsync(cnt8, 0, sizeof(int) * (size_t)NCOPY * N_NODES, stream);

    hist_kernel<<<HIST_BLKS, 256, 0, stream>>>(dst, cnt8, rank);

    node_wave<<<1024, 256, 0, stream>>>(
        d_u, p_u, w_v, a, b, h_src, h_dst, wv);

    scan1_kernel<<<N_SCAN_BLKS, SCAN_BLK, 0, stream>>>(cnt8, cnt, row, bsum);
    scan23_kernel<<<(N_NODES + 255) / 256, 256, 0, stream>>>(row, bsum);

    build_kernel<<<(N_EDGES + 255) / 256, 256, 0, stream>>>(
        src, dst, row, cnt8, rank, csr_src);

    node_gather<<<(N_NODES * 64 + 255) / 256, 256, 0, stream>>>(
        row, cnt, csr_src, h_src, h_dst, wv, out);
}